// Round 1
// baseline (804.142 us; speedup 1.0000x reference)
//
#include <hip/hip_runtime.h>
#include <cstdint>

typedef __attribute__((ext_vector_type(8))) __bf16 bf16x8;
typedef __attribute__((ext_vector_type(4))) float f32x4;

__device__ __forceinline__ unsigned short f2bf(float f) {
  unsigned u = __float_as_uint(f);
  unsigned r = (u + 0x7FFFu + ((u >> 16) & 1u)) >> 16;  // RNE
  return (unsigned short)r;
}

__device__ __forceinline__ __attribute__((address_space(3))) void* to_lds(void* p) {
  return (__attribute__((address_space(3))) void*)p;
}
__device__ __forceinline__ const __attribute__((address_space(1))) void* to_glb(const void* p) {
  return (const __attribute__((address_space(1))) void*)p;
}

// ---------------- transpose: fp32 in[R,C] -> bf16 out[C,R] ----------------
__global__ void k_transpose_bf16(const float* __restrict__ in, unsigned short* __restrict__ out,
                                 int R, int C) {
  __shared__ float tile[32][33];
  int c0 = blockIdx.x * 32, r0 = blockIdx.y * 32;
  int tx = threadIdx.x, ty = threadIdx.y;  // block (32,8)
  #pragma unroll
  for (int i = 0; i < 32; i += 8)
    tile[ty + i][tx] = in[(size_t)(r0 + ty + i) * C + c0 + tx];
  __syncthreads();
  #pragma unroll
  for (int i = 0; i < 32; i += 8)
    out[(size_t)(c0 + ty + i) * R + r0 + tx] = f2bf(tile[tx][ty + i]);
}

// ---------------- fp32 -> bf16 contiguous ----------------
__global__ void k_convert_bf16(const float4* __restrict__ in, ushort4* __restrict__ out, int n4) {
  int i = blockIdx.x * blockDim.x + threadIdx.x;
  if (i < n4) {
    float4 v = in[i];
    ushort4 o; o.x = f2bf(v.x); o.y = f2bf(v.y); o.z = f2bf(v.z); o.w = f2bf(v.w);
    out[i] = o;
  }
}

// ---------------- X fp32 [T,1024] -> bf16 into gate_in[T,2048] cols 0..1023 ----------------
__global__ void k_stage_x(const float4* __restrict__ X, unsigned short* __restrict__ gate_in, int n4) {
  int i = blockIdx.x * blockDim.x + threadIdx.x;
  if (i < n4) {
    int flat = i << 2;
    int row = flat >> 10, col = flat & 1023;
    float4 v = X[i];
    ushort4 o; o.x = f2bf(v.x); o.y = f2bf(v.y); o.z = f2bf(v.z); o.w = f2bf(v.w);
    *(ushort4*)(gate_in + (size_t)row * 2048 + col) = o;
  }
}

__global__ void k_concat_bias(const float* __restrict__ bk, const float* __restrict__ bv,
                              float* __restrict__ bkv) {
  int i = blockIdx.x * blockDim.x + threadIdx.x;
  if (i < 2048) bkv[i] = (i < 1024) ? bk[i] : bv[i - 1024];
}

// ---------------- row l2-normalize: Q fp32 [rows,1024] -> bf16 ----------------
__global__ void k_norm_rows(const float4* __restrict__ Q, unsigned short* __restrict__ Qn) {
  int row = blockIdx.x;
  int tid = threadIdx.x;  // 256
  float4 v = Q[(size_t)row * 256 + tid];
  float s = v.x * v.x + v.y * v.y + v.z * v.z + v.w * v.w;
  #pragma unroll
  for (int m = 32; m; m >>= 1) s += __shfl_xor(s, m, 64);
  __shared__ float red[4];
  if ((tid & 63) == 0) red[tid >> 6] = s;
  __syncthreads();
  float tot = red[0] + red[1] + red[2] + red[3];
  float inv = 1.0f / fmaxf(sqrtf(tot), 1e-12f);
  ushort4 o; o.x = f2bf(v.x * inv); o.y = f2bf(v.y * inv);
  o.z = f2bf(v.z * inv); o.w = f2bf(v.w * inv);
  *(ushort4*)(Qn + (size_t)row * 1024 + tid * 4) = o;
}

// ---------------- KV fp32 [512,2048] -> Kn bf16 [512,1024] (normalized), Vt bf16 [1024,512] ----------------
__global__ void k_post_kv(const float4* __restrict__ KV, unsigned short* __restrict__ Kn,
                          unsigned short* __restrict__ Vt) {
  int row = blockIdx.x;   // 512
  int tid = threadIdx.x;  // 256
  const float4* r = KV + (size_t)row * 512;
  float4 k4 = r[tid];
  float4 v4 = r[256 + tid];
  float s = k4.x * k4.x + k4.y * k4.y + k4.z * k4.z + k4.w * k4.w;
  #pragma unroll
  for (int m = 32; m; m >>= 1) s += __shfl_xor(s, m, 64);
  __shared__ float red[4];
  if ((tid & 63) == 0) red[tid >> 6] = s;
  __syncthreads();
  float tot = red[0] + red[1] + red[2] + red[3];
  float inv = 1.0f / fmaxf(sqrtf(tot), 1e-12f);
  ushort4 o; o.x = f2bf(k4.x * inv); o.y = f2bf(k4.y * inv);
  o.z = f2bf(k4.z * inv); o.w = f2bf(k4.w * inv);
  *(ushort4*)(Kn + (size_t)row * 1024 + tid * 4) = o;
  int vc = tid * 4;
  Vt[(size_t)(vc + 0) * 512 + row] = f2bf(v4.x);
  Vt[(size_t)(vc + 1) * 512 + row] = f2bf(v4.y);
  Vt[(size_t)(vc + 2) * 512 + row] = f2bf(v4.z);
  Vt[(size_t)(vc + 3) * 512 + row] = f2bf(v4.w);
}

// ---------------- softmax over rows of S fp32 [T,512] -> w bf16 [T,512] ----------------
__global__ void k_softmax(const float4* __restrict__ S, unsigned short* __restrict__ W) {
  int tid = threadIdx.x;
  int wv = tid >> 6, lane = tid & 63;
  int row = blockIdx.x * 4 + wv;
  const float4* sr = S + (size_t)row * 128;
  float4 a = sr[lane], b = sr[64 + lane];
  float m = fmaxf(fmaxf(fmaxf(a.x, a.y), fmaxf(a.z, a.w)),
                  fmaxf(fmaxf(b.x, b.y), fmaxf(b.z, b.w)));
  #pragma unroll
  for (int o = 32; o; o >>= 1) m = fmaxf(m, __shfl_xor(m, o, 64));
  a.x = __expf(a.x - m); a.y = __expf(a.y - m); a.z = __expf(a.z - m); a.w = __expf(a.w - m);
  b.x = __expf(b.x - m); b.y = __expf(b.y - m); b.z = __expf(b.z - m); b.w = __expf(b.w - m);
  float s = a.x + a.y + a.z + a.w + b.x + b.y + b.z + b.w;
  #pragma unroll
  for (int o = 32; o; o >>= 1) s += __shfl_xor(s, o, 64);
  float inv = 1.0f / s;
  ushort4 oa, ob;
  oa.x = f2bf(a.x * inv); oa.y = f2bf(a.y * inv); oa.z = f2bf(a.z * inv); oa.w = f2bf(a.w * inv);
  ob.x = f2bf(b.x * inv); ob.y = f2bf(b.y * inv); ob.z = f2bf(b.z * inv); ob.w = f2bf(b.w * inv);
  ushort4* wr = (ushort4*)(W + (size_t)row * 512);
  wr[lane] = oa; wr[64 + lane] = ob;
}

// ---------------- bf16 MFMA GEMM: C[M,N] = A[M,K] * B^T stored as [N,K], + bias, * scale ----------------
// 128x128 tile / block, 4 waves in 2x2, 64x64 per wave, BK=64, 16x16x32 MFMA.
// LDS chunks (8 bf16 = 16B) XOR-swizzled: phys_chunk = logical_chunk ^ (row&7),
// compatible with global_load_lds's forced "base + lane*16" layout (lane fetches
// the swizzled global chunk instead).
// MODE 0: store fp32 C. MODE 2: + bf16 copy to Cb (ldcb). MODE 3: sigmoid gate
// epilogue: out = g*X + (1-g)*R, in-place safe (element-exclusive).
template <int MODE>
__global__ __launch_bounds__(256, 2) void k_gemm(
    const unsigned short* __restrict__ A, int lda,
    const unsigned short* __restrict__ B, int ldb,
    const float* __restrict__ bias, float scale,
    float* __restrict__ C, int ldc,
    unsigned short* __restrict__ Cb, int ldcb,
    const float* __restrict__ Xf, const float* __restrict__ Rf,
    int K) {
  __shared__ __align__(16) unsigned short As[128 * 64];
  __shared__ __align__(16) unsigned short Bs[128 * 64];
  const int tid = threadIdx.x;
  const int lane = tid & 63, w = tid >> 6;
  const int m0 = blockIdx.y * 128, n0 = blockIdx.x * 128;

  // staging: wave w, instr i covers tile rows [i*32 + w*8, +8); lane l -> row +(l>>3),
  // LDS phys chunk (l&7); fetch global logical chunk (l&7)^(l>>3)
  const int srow = lane >> 3;
  const int schunk = (lane & 7) ^ srow;
  const unsigned short* gA = A + (size_t)(m0 + w * 8 + srow) * lda + schunk * 8;
  const unsigned short* gB = B + (size_t)(n0 + w * 8 + srow) * ldb + schunk * 8;
  unsigned short* lA = As + (w * 8) * 64;
  unsigned short* lB = Bs + (w * 8) * 64;

  f32x4 acc[4][4];
  f32x4 zero = {0.f, 0.f, 0.f, 0.f};
  #pragma unroll
  for (int i = 0; i < 4; ++i)
    #pragma unroll
    for (int j = 0; j < 4; ++j) acc[i][j] = zero;

  const int fr = lane & 15, q = lane >> 4;
  const int wr = (w >> 1) * 64, wc = (w & 1) * 64;

  for (int k0 = 0; k0 < K; k0 += 64) {
    #pragma unroll
    for (int i = 0; i < 4; ++i) {
      __builtin_amdgcn_global_load_lds(to_glb(gA + (size_t)i * 32 * lda + k0),
                                       to_lds(lA + i * 32 * 64), 16, 0, 0);
      __builtin_amdgcn_global_load_lds(to_glb(gB + (size_t)i * 32 * ldb + k0),
                                       to_lds(lB + i * 32 * 64), 16, 0, 0);
    }
    __syncthreads();  // drains vmcnt before barrier (compiler-enforced)
    #pragma unroll
    for (int ks = 0; ks < 2; ++ks) {
      bf16x8 af[4], bfr[4];
      const int p = (ks * 4 + q) ^ (lane & 7);
      #pragma unroll
      for (int mi = 0; mi < 4; ++mi) {
        af[mi] = *(const bf16x8*)(As + (wr + mi * 16 + fr) * 64 + p * 8);
        bfr[mi] = *(const bf16x8*)(Bs + (wc + mi * 16 + fr) * 64 + p * 8);
      }
      #pragma unroll
      for (int mi = 0; mi < 4; ++mi)
        #pragma unroll
        for (int ni = 0; ni < 4; ++ni)
          acc[mi][ni] = __builtin_amdgcn_mfma_f32_16x16x32_bf16(af[mi], bfr[ni], acc[mi][ni], 0, 0, 0);
    }
    __syncthreads();
  }

  // epilogue: D[row = q*4+r][col = lane&15] per 16x16 tile
  #pragma unroll
  for (int ni = 0; ni < 4; ++ni) {
    const int gc = n0 + wc + ni * 16 + fr;
    const float bv = bias ? bias[gc] : 0.0f;
    #pragma unroll
    for (int mi = 0; mi < 4; ++mi) {
      #pragma unroll
      for (int r = 0; r < 4; ++r) {
        const int gr = m0 + wr + mi * 16 + q * 4 + r;
        const size_t idx = (size_t)gr * ldc + gc;
        float c = acc[mi][ni][r] * scale + bv;
        if (MODE == 0) {
          C[idx] = c;
        } else if (MODE == 2) {
          C[idx] = c;
          Cb[(size_t)gr * ldcb + gc] = f2bf(c);
        } else {
          float g = 1.0f / (1.0f + __expf(-c));
          float x = Xf[idx];
          float rr = Rf[idx];
          C[idx] = g * x + (1.0f - g) * rr;
        }
      }
    }
  }
}

extern "C" void kernel_launch(void* const* d_in, const int* in_sizes, int n_in,
                              void* d_out, int out_size, void* d_ws, size_t ws_size,
                              hipStream_t stream) {
  const float* X   = (const float*)d_in[0];
  const float* mem = (const float*)d_in[1];
  const float* Wq  = (const float*)d_in[2];
  const float* bq  = (const float*)d_in[3];
  const float* Wk  = (const float*)d_in[4];
  const float* bk  = (const float*)d_in[5];
  const float* Wv  = (const float*)d_in[6];
  const float* bv  = (const float*)d_in[7];
  const float* Wg  = (const float*)d_in[8];
  const float* bg  = (const float*)d_in[9];
  float* out = (float*)d_out;

  const int T = 32768, D = 1024, NS = 512;

  char* p = (char*)d_ws;
  auto alloc = [&](size_t b) { char* r = p; p += (b + 255) & ~(size_t)255; return r; };
  unsigned short* WqT    = (unsigned short*)alloc((size_t)D * D * 2);
  unsigned short* WkvT   = (unsigned short*)alloc((size_t)2 * D * D * 2);
  unsigned short* WgT    = (unsigned short*)alloc((size_t)D * 2 * D * 2);
  unsigned short* memb   = (unsigned short*)alloc((size_t)NS * D * 2);
  float*          bkv    = (float*)alloc((size_t)2 * D * 4);
  float*          KV     = (float*)alloc((size_t)NS * 2 * D * 4);
  unsigned short* Kn     = (unsigned short*)alloc((size_t)NS * D * 2);
  unsigned short* Vt     = (unsigned short*)alloc((size_t)D * NS * 2);
  unsigned short* gatein = (unsigned short*)alloc((size_t)T * 2 * D * 2);
  unsigned short* QnW    = (unsigned short*)alloc((size_t)T * D * 2);   // Qn, later reused for w
  float*          bigA   = (float*)alloc((size_t)T * D * 4);            // Q fp32, later S fp32

  // --- prep: weight transposes to [N,K] bf16, converts ---
  k_transpose_bf16<<<dim3(32, 32), dim3(32, 8), 0, stream>>>(Wq, WqT, D, D);
  k_transpose_bf16<<<dim3(32, 32), dim3(32, 8), 0, stream>>>(Wk, WkvT, D, D);
  k_transpose_bf16<<<dim3(32, 32), dim3(32, 8), 0, stream>>>(Wv, WkvT + (size_t)D * D, D, D);
  k_transpose_bf16<<<dim3(32, 64), dim3(32, 8), 0, stream>>>(Wg, WgT, 2 * D, D);
  k_convert_bf16<<<512, 256, 0, stream>>>((const float4*)mem, (ushort4*)memb, NS * D / 4);
  k_concat_bias<<<8, 256, 0, stream>>>(bk, bv, bkv);
  k_stage_x<<<T * D / 4 / 256, 256, 0, stream>>>((const float4*)X, gatein, T * D / 4);

  // --- K,V: [512,2048] = memb[512,1024] @ [Wk|Wv], bias [bk|bv] ---
  k_gemm<0><<<dim3(2 * D / 128, NS / 128), 256, 0, stream>>>(
      memb, D, WkvT, D, bkv, 1.0f, KV, 2 * D, nullptr, 0, nullptr, nullptr, D);
  k_post_kv<<<NS, 256, 0, stream>>>((const float4*)KV, Kn, Vt);

  // --- Q = X @ Wq + bq (A = bf16 X inside gate_in, lda=2048) ---
  k_gemm<0><<<dim3(D / 128, T / 128), 256, 0, stream>>>(
      gatein, 2 * D, WqT, D, bq, 1.0f, bigA, D, nullptr, 0, nullptr, nullptr, D);
  k_norm_rows<<<T, 256, 0, stream>>>((const float4*)bigA, QnW);

  // --- scores = Qn @ Kn^T / 32 (B = Kn row-major is already [N,K]) ---
  k_gemm<0><<<dim3(NS / 128, T / 128), 256, 0, stream>>>(
      QnW, D, Kn, D, nullptr, 0.03125f, bigA, NS, nullptr, 0, nullptr, nullptr, D);
  k_softmax<<<T / 4, 256, 0, stream>>>((const float4*)bigA, QnW);  // w overwrites Qn region

  // --- R = w @ V : fp32 to d_out, bf16 copy into gate_in cols 1024.. ---
  k_gemm<2><<<dim3(D / 128, T / 128), 256, 0, stream>>>(
      QnW, NS, Vt, NS, nullptr, 1.0f, out, D, gatein + D, 2 * D, nullptr, nullptr, NS);

  // --- gate: g = sigmoid([X,R] @ Wg + bg); out = g*X + (1-g)*R (in-place on d_out) ---
  k_gemm<3><<<dim3(D / 128, T / 128), 256, 0, stream>>>(
      gatein, 2 * D, WgT, 2 * D, bg, 1.0f, out, D, nullptr, 0, X, out, 2 * D);

  (void)in_sizes; (void)n_in; (void)out_size; (void)ws_size;
}

// Round 2
// 636.489 us; speedup vs baseline: 1.2634x; 1.2634x over previous
//
#include <hip/hip_runtime.h>
#include <cstdint>

typedef __attribute__((ext_vector_type(8))) __bf16 bf16x8;
typedef __attribute__((ext_vector_type(4))) float f32x4;

__device__ __forceinline__ unsigned short f2bf(float f) {
  unsigned u = __float_as_uint(f);
  unsigned r = (u + 0x7FFFu + ((u >> 16) & 1u)) >> 16;  // RNE
  return (unsigned short)r;
}
__device__ __forceinline__ float bf2f(unsigned short u) {
  return __uint_as_float(((unsigned)u) << 16);
}

__device__ __forceinline__ __attribute__((address_space(3))) void* to_lds(void* p) {
  return (__attribute__((address_space(3))) void*)p;
}
__device__ __forceinline__ const __attribute__((address_space(1))) void* to_glb(const void* p) {
  return (const __attribute__((address_space(1))) void*)p;
}

// ---------------- transpose: fp32 in[R,C] -> bf16 out[C,R] ----------------
__global__ void k_transpose_bf16(const float* __restrict__ in, unsigned short* __restrict__ out,
                                 int R, int C) {
  __shared__ float tile[32][33];
  int c0 = blockIdx.x * 32, r0 = blockIdx.y * 32;
  int tx = threadIdx.x, ty = threadIdx.y;  // block (32,8)
  #pragma unroll
  for (int i = 0; i < 32; i += 8)
    tile[ty + i][tx] = in[(size_t)(r0 + ty + i) * C + c0 + tx];
  __syncthreads();
  #pragma unroll
  for (int i = 0; i < 32; i += 8)
    out[(size_t)(c0 + ty + i) * R + r0 + tx] = f2bf(tile[tx][ty + i]);
}

// ---------------- fp32 -> bf16 contiguous ----------------
__global__ void k_convert_bf16(const float4* __restrict__ in, ushort4* __restrict__ out, int n4) {
  int i = blockIdx.x * blockDim.x + threadIdx.x;
  if (i < n4) {
    float4 v = in[i];
    ushort4 o; o.x = f2bf(v.x); o.y = f2bf(v.y); o.z = f2bf(v.z); o.w = f2bf(v.w);
    out[i] = o;
  }
}

// ---------------- X fp32 [T,1024] -> bf16 into gate_in[T,2048] cols 0..1023 ----------------
__global__ void k_stage_x(const float4* __restrict__ X, unsigned short* __restrict__ gate_in, int n4) {
  int i = blockIdx.x * blockDim.x + threadIdx.x;
  if (i < n4) {
    int flat = i << 2;
    int row = flat >> 10, col = flat & 1023;
    float4 v = X[i];
    ushort4 o; o.x = f2bf(v.x); o.y = f2bf(v.y); o.z = f2bf(v.z); o.w = f2bf(v.w);
    *(ushort4*)(gate_in + (size_t)row * 2048 + col) = o;
  }
}

__global__ void k_concat_bias(const float* __restrict__ bk, const float* __restrict__ bv,
                              float* __restrict__ bkv) {
  int i = blockIdx.x * blockDim.x + threadIdx.x;
  if (i < 2048) bkv[i] = (i < 1024) ? bk[i] : bv[i - 1024];
}

// ---------------- KV fp32 [512,2048] -> Kn bf16 [512,1024] (normalized), Vt bf16 [1024,512] ----------------
__global__ void k_post_kv(const float4* __restrict__ KV, unsigned short* __restrict__ Kn,
                          unsigned short* __restrict__ Vt) {
  int row = blockIdx.x;   // 512
  int tid = threadIdx.x;  // 256
  const float4* r = KV + (size_t)row * 512;
  float4 k4 = r[tid];
  float4 v4 = r[256 + tid];
  float s = k4.x * k4.x + k4.y * k4.y + k4.z * k4.z + k4.w * k4.w;
  #pragma unroll
  for (int m = 32; m; m >>= 1) s += __shfl_xor(s, m, 64);
  __shared__ float red[4];
  if ((tid & 63) == 0) red[tid >> 6] = s;
  __syncthreads();
  float tot = red[0] + red[1] + red[2] + red[3];
  float inv = 1.0f / fmaxf(sqrtf(tot), 1e-12f);
  ushort4 o; o.x = f2bf(k4.x * inv); o.y = f2bf(k4.y * inv);
  o.z = f2bf(k4.z * inv); o.w = f2bf(k4.w * inv);
  *(ushort4*)(Kn + (size_t)row * 1024 + tid * 4) = o;
  int vc = tid * 4;
  Vt[(size_t)(vc + 0) * 512 + row] = f2bf(v4.x);
  Vt[(size_t)(vc + 1) * 512 + row] = f2bf(v4.y);
  Vt[(size_t)(vc + 2) * 512 + row] = f2bf(v4.z);
  Vt[(size_t)(vc + 3) * 512 + row] = f2bf(v4.w);
}

// ---------------- softmax with per-row temperature: w = softmax(S * alpha_row) ----------------
// alpha_row = (1/32) * rsqrt(norm2[row])  — folds in Q l2-normalization.
__global__ void k_softmax(const float4* __restrict__ S, const float* __restrict__ norm2,
                          unsigned short* __restrict__ W) {
  int tid = threadIdx.x;
  int wv = tid >> 6, lane = tid & 63;
  int row = blockIdx.x * 4 + wv;
  float alpha = 0.03125f * rsqrtf(fmaxf(norm2[row], 1e-24f));
  const float4* sr = S + (size_t)row * 128;
  float4 a = sr[lane], b = sr[64 + lane];
  a.x *= alpha; a.y *= alpha; a.z *= alpha; a.w *= alpha;
  b.x *= alpha; b.y *= alpha; b.z *= alpha; b.w *= alpha;
  float m = fmaxf(fmaxf(fmaxf(a.x, a.y), fmaxf(a.z, a.w)),
                  fmaxf(fmaxf(b.x, b.y), fmaxf(b.z, b.w)));
  #pragma unroll
  for (int o = 32; o; o >>= 1) m = fmaxf(m, __shfl_xor(m, o, 64));
  a.x = __expf(a.x - m); a.y = __expf(a.y - m); a.z = __expf(a.z - m); a.w = __expf(a.w - m);
  b.x = __expf(b.x - m); b.y = __expf(b.y - m); b.z = __expf(b.z - m); b.w = __expf(b.w - m);
  float s = a.x + a.y + a.z + a.w + b.x + b.y + b.z + b.w;
  #pragma unroll
  for (int o = 32; o; o >>= 1) s += __shfl_xor(s, o, 64);
  float inv = 1.0f / s;
  ushort4 oa, ob;
  oa.x = f2bf(a.x * inv); oa.y = f2bf(a.y * inv); oa.z = f2bf(a.z * inv); oa.w = f2bf(a.w * inv);
  ob.x = f2bf(b.x * inv); ob.y = f2bf(b.y * inv); ob.z = f2bf(b.z * inv); ob.w = f2bf(b.w * inv);
  ushort4* wr = (ushort4*)(W + (size_t)row * 512);
  wr[lane] = oa; wr[64 + lane] = ob;
}

// ---------------- bf16 MFMA GEMM: C[M,N] = A[M,K] * B^T stored as [N,K] ----------------
// 128x128 tile, 4 waves 2x2, BK=64, 16x16x32 MFMA, XOR-swizzled LDS chunks,
// global_load_lds width 16. XCD-aware tile remap: all N-blocks of one M-panel
// share f%8 (same XCD under round-robin dispatch) and are temporally adjacent,
// so the A panel is fetched into exactly one L2.
// MODE 0: C fp32 = acc*scale + bias.
// MODE 1: Cb bf16 = acc + bias; atomic-accumulate row sum-of-squares into Cnorm.
// MODE 2: Cb bf16 = acc.
// MODE 3: g = sigmoid(acc+bias); x,r read bf16 from Cb[gr][gc], Cb[gr][1024+gc];
//         C fp32 = g*x + (1-g)*r.
template <int MODE>
__global__ __launch_bounds__(256, 2) void k_gemm(
    const unsigned short* __restrict__ A, int lda,
    const unsigned short* __restrict__ B, int ldb,
    const float* __restrict__ bias, float scale,
    float* __restrict__ C, int ldc,
    unsigned short* __restrict__ Cb, int ldcb,
    float* __restrict__ Cnorm,
    int K) {
  __shared__ __align__(16) unsigned short As[128 * 64];
  __shared__ __align__(16) unsigned short Bs[128 * 64];
  const int tid = threadIdx.x;
  const int lane = tid & 63, w = tid >> 6;

  // XCD-aware tile remap (requires gridDim.y % 8 == 0, else identity)
  int mt, nt;
  {
    int f = blockIdx.y * gridDim.x + blockIdx.x;
    int NTg = gridDim.x, MTg = gridDim.y;
    if ((MTg & 7) == 0) {
      int xcd = f & 7;
      int j = f >> 3;
      nt = j % NTg;
      mt = (j / NTg) * 8 + xcd;
    } else {
      mt = blockIdx.y; nt = blockIdx.x;
    }
  }
  const int m0 = mt * 128, n0 = nt * 128;

  const int srow = lane >> 3;
  const int schunk = (lane & 7) ^ srow;
  const unsigned short* gA = A + (size_t)(m0 + w * 8 + srow) * lda + schunk * 8;
  const unsigned short* gB = B + (size_t)(n0 + w * 8 + srow) * ldb + schunk * 8;
  unsigned short* lA = As + (w * 8) * 64;
  unsigned short* lB = Bs + (w * 8) * 64;

  f32x4 acc[4][4];
  f32x4 zero = {0.f, 0.f, 0.f, 0.f};
  #pragma unroll
  for (int i = 0; i < 4; ++i)
    #pragma unroll
    for (int j = 0; j < 4; ++j) acc[i][j] = zero;

  const int fr = lane & 15, q = lane >> 4;
  const int wr = (w >> 1) * 64, wc = (w & 1) * 64;

  for (int k0 = 0; k0 < K; k0 += 64) {
    #pragma unroll
    for (int i = 0; i < 4; ++i) {
      __builtin_amdgcn_global_load_lds(to_glb(gA + (size_t)i * 32 * lda + k0),
                                       to_lds(lA + i * 32 * 64), 16, 0, 0);
      __builtin_amdgcn_global_load_lds(to_glb(gB + (size_t)i * 32 * ldb + k0),
                                       to_lds(lB + i * 32 * 64), 16, 0, 0);
    }
    __syncthreads();
    #pragma unroll
    for (int ks = 0; ks < 2; ++ks) {
      bf16x8 af[4], bfr[4];
      const int p = (ks * 4 + q) ^ (lane & 7);
      #pragma unroll
      for (int mi = 0; mi < 4; ++mi) {
        af[mi] = *(const bf16x8*)(As + (wr + mi * 16 + fr) * 64 + p * 8);
        bfr[mi] = *(const bf16x8*)(Bs + (wc + mi * 16 + fr) * 64 + p * 8);
      }
      #pragma unroll
      for (int mi = 0; mi < 4; ++mi)
        #pragma unroll
        for (int ni = 0; ni < 4; ++ni)
          acc[mi][ni] = __builtin_amdgcn_mfma_f32_16x16x32_bf16(af[mi], bfr[ni], acc[mi][ni], 0, 0, 0);
    }
    __syncthreads();
  }

  if (MODE == 1) {
    // bf16 store + per-row sum-of-squares accumulation (for deferred l2-norm)
    #pragma unroll
    for (int mi = 0; mi < 4; ++mi) {
      float s2[4] = {0.f, 0.f, 0.f, 0.f};
      #pragma unroll
      for (int ni = 0; ni < 4; ++ni) {
        const int gc = n0 + wc + ni * 16 + fr;
        const float bv = bias[gc];
        #pragma unroll
        for (int r = 0; r < 4; ++r) {
          const int gr = m0 + wr + mi * 16 + q * 4 + r;
          float c = acc[mi][ni][r] + bv;
          Cb[(size_t)gr * ldcb + gc] = f2bf(c);
          s2[r] += c * c;
        }
      }
      #pragma unroll
      for (int r = 0; r < 4; ++r) {
        float v = s2[r];
        v += __shfl_xor(v, 1, 64);
        v += __shfl_xor(v, 2, 64);
        v += __shfl_xor(v, 4, 64);
        v += __shfl_xor(v, 8, 64);
        if (fr == 0) atomicAdd(Cnorm + (m0 + wr + mi * 16 + q * 4 + r), v);
      }
    }
  } else {
    #pragma unroll
    for (int ni = 0; ni < 4; ++ni) {
      const int gc = n0 + wc + ni * 16 + fr;
      const float bv = bias ? bias[gc] : 0.0f;
      #pragma unroll
      for (int mi = 0; mi < 4; ++mi) {
        #pragma unroll
        for (int r = 0; r < 4; ++r) {
          const int gr = m0 + wr + mi * 16 + q * 4 + r;
          float c = acc[mi][ni][r] * scale + bv;
          if (MODE == 0) {
            C[(size_t)gr * ldc + gc] = c;
          } else if (MODE == 2) {
            Cb[(size_t)gr * ldcb + gc] = f2bf(c);
          } else {  // MODE 3
            float g = 1.0f / (1.0f + __expf(-c));
            float x = bf2f(Cb[(size_t)gr * ldcb + gc]);
            float rr = bf2f(Cb[(size_t)gr * ldcb + 1024 + gc]);
            C[(size_t)gr * ldc + gc] = g * x + (1.0f - g) * rr;
          }
        }
      }
    }
  }
}

extern "C" void kernel_launch(void* const* d_in, const int* in_sizes, int n_in,
                              void* d_out, int out_size, void* d_ws, size_t ws_size,
                              hipStream_t stream) {
  const float* X   = (const float*)d_in[0];
  const float* mem = (const float*)d_in[1];
  const float* Wq  = (const float*)d_in[2];
  const float* bq  = (const float*)d_in[3];
  const float* Wk  = (const float*)d_in[4];
  const float* bk  = (const float*)d_in[5];
  const float* Wv  = (const float*)d_in[6];
  const float* bv  = (const float*)d_in[7];
  const float* Wg  = (const float*)d_in[8];
  const float* bg  = (const float*)d_in[9];
  float* out = (float*)d_out;

  const int T = 32768, D = 1024, NS = 512;

  char* p = (char*)d_ws;
  auto alloc = [&](size_t b) { char* r = p; p += (b + 255) & ~(size_t)255; return r; };
  unsigned short* WqT    = (unsigned short*)alloc((size_t)D * D * 2);
  unsigned short* WkvT   = (unsigned short*)alloc((size_t)2 * D * D * 2);
  unsigned short* WgT    = (unsigned short*)alloc((size_t)D * 2 * D * 2);
  unsigned short* memb   = (unsigned short*)alloc((size_t)NS * D * 2);
  float*          bkv    = (float*)alloc((size_t)2 * D * 4);
  float*          KV     = (float*)alloc((size_t)NS * 2 * D * 4);
  unsigned short* Kn     = (unsigned short*)alloc((size_t)NS * D * 2);
  unsigned short* Vt     = (unsigned short*)alloc((size_t)D * NS * 2);
  unsigned short* gatein = (unsigned short*)alloc((size_t)T * 2 * D * 2);  // [T,2048]: X | R
  unsigned short* Qb     = (unsigned short*)alloc((size_t)T * D * 2);      // Q bf16 (unnormalized)
  unsigned short* Wsm    = (unsigned short*)alloc((size_t)T * NS * 2);     // softmax weights bf16
  float*          S      = (float*)alloc((size_t)T * NS * 4);              // scores fp32
  float*          norm2  = (float*)alloc((size_t)T * 4);                   // ||Q_row||^2

  hipMemsetAsync(norm2, 0, (size_t)T * 4, stream);

  // --- prep: weight transposes to [N,K] bf16, converts ---
  k_transpose_bf16<<<dim3(32, 32), dim3(32, 8), 0, stream>>>(Wq, WqT, D, D);
  k_transpose_bf16<<<dim3(32, 32), dim3(32, 8), 0, stream>>>(Wk, WkvT, D, D);
  k_transpose_bf16<<<dim3(32, 32), dim3(32, 8), 0, stream>>>(Wv, WkvT + (size_t)D * D, D, D);
  k_transpose_bf16<<<dim3(32, 64), dim3(32, 8), 0, stream>>>(Wg, WgT, 2 * D, D);
  k_convert_bf16<<<512, 256, 0, stream>>>((const float4*)mem, (ushort4*)memb, NS * D / 4);
  k_concat_bias<<<8, 256, 0, stream>>>(bk, bv, bkv);
  k_stage_x<<<T * D / 4 / 256, 256, 0, stream>>>((const float4*)X, gatein, T * D / 4);

  // --- K,V: [512,2048] = memb @ [Wk|Wv] + [bk|bv] ---
  k_gemm<0><<<dim3(2 * D / 128, NS / 128), 256, 0, stream>>>(
      memb, D, WkvT, D, bkv, 1.0f, KV, 2 * D, nullptr, 0, nullptr, D);
  k_post_kv<<<NS, 256, 0, stream>>>((const float4*)KV, Kn, Vt);

  // --- Q = X @ Wq + bq -> bf16 Qb + row norms (normalization deferred to softmax) ---
  k_gemm<1><<<dim3(D / 128, T / 128), 256, 0, stream>>>(
      gatein, 2 * D, WqT, D, bq, 1.0f, nullptr, 0, Qb, D, norm2, D);

  // --- scores_raw = Q @ Kn^T (temperature applied in softmax) ---
  k_gemm<0><<<dim3(NS / 128, T / 128), 256, 0, stream>>>(
      Qb, D, Kn, D, nullptr, 1.0f, S, NS, nullptr, 0, nullptr, D);
  k_softmax<<<T / 4, 256, 0, stream>>>((const float4*)S, norm2, Wsm);

  // --- R = w @ V -> bf16 into gate_in cols 1024.. ---
  k_gemm<2><<<dim3(D / 128, T / 128), 256, 0, stream>>>(
      Wsm, NS, Vt, NS, nullptr, 1.0f, nullptr, 0, gatein + D, 2 * D, nullptr, NS);

  // --- gate: g = sigmoid([X,R] @ Wg + bg); out = g*x + (1-g)*r (x,r bf16 from gate_in) ---
  k_gemm<3><<<dim3(D / 128, T / 128), 256, 0, stream>>>(
      gatein, 2 * D, WgT, 2 * D, bg, 1.0f, out, D, gatein, 2 * D, nullptr, 2 * D);

  (void)in_sizes; (void)n_in; (void)out_size; (void)ws_size;
}